// Round 15
// baseline (252.444 us; speedup 1.0000x reference)
//
#include <hip/hip_runtime.h>
#include <hip/hip_bf16.h>

// LSTM block, fused. Inputs fp32, outputs fp32. bf16 MFMA internally.
// r12 structure (weights-in-regs Breg 128/wave + Wreg 16, all prefetch in LDS
// via global_load_lds, ONE barrier per 32-row tile) + GEMM2 software-pipelined
// one tile back: body t runs GEMM2(t-1)+h-epilogue(t-1) interleaved with
// elementwise(t). o-gate crosses the boundary packed bf16 via PURE C++ f2bf
// (r13/r14's cvtpk-asm carried state was the prime corruption suspect).
// Dummy A-DMA at T==30 keeps op counts uniform. Barrier: waitcnt lgkmcnt(0)
// vmcnt(VMC); sched_barrier(0) BEFORE and AFTER s_barrier.
// LDS 144K: abuf bf16 2x16K | land fp32 2x32K | clds 2x16K | c_ex 2x8K.

typedef __attribute__((ext_vector_type(8))) short bf16x8;   // 8 bf16 = 4 VGPRs
typedef __attribute__((ext_vector_type(4))) float f32x4;

#define AB0   0
#define AB1   16384
#define LAND0 32768
#define LAND1 65536
#define CLDS0 98304
#define CLDS1 114688
#define CEX0  131072
#define CEX1  139264

static __device__ __forceinline__ unsigned short f2bf(float f) {
    unsigned int u = __builtin_bit_cast(unsigned int, f);
    u += 0x7FFFu + ((u >> 16) & 1u);      // RNE
    return (unsigned short)(u >> 16);
}

static __device__ __forceinline__ unsigned int cvtpk(float lo, float hi) {
    unsigned int r;
    asm("v_cvt_pk_bf16_f32 %0, %1, %2" : "=v"(r) : "v"(lo), "v"(hi));
    return r;
}

static __device__ __forceinline__ bf16x8 cvt8(f32x4 a, f32x4 b) {
    union { bf16x8 v; unsigned int w[4]; } r;
    r.w[0] = cvtpk(a[0], a[1]);
    r.w[1] = cvtpk(a[2], a[3]);
    r.w[2] = cvtpk(b[0], b[1]);
    r.w[3] = cvtpk(b[2], b[3]);
    return r.v;
}

static __device__ __forceinline__ float obf_lo(unsigned int u) {
    return __builtin_bit_cast(float, u << 16);
}
static __device__ __forceinline__ float obf_hi(unsigned int u) {
    return __builtin_bit_cast(float, u & 0xFFFF0000u);
}

static __device__ __forceinline__ float fsig(float x) {
    float e = __builtin_amdgcn_exp2f(-1.44269504f * x);
    return __builtin_amdgcn_rcpf(1.0f + e);
}
static __device__ __forceinline__ float ftanh(float x) {
    float e = __builtin_amdgcn_exp2f(2.8853900818f * x);
    return 1.0f - 2.0f * __builtin_amdgcn_rcpf(e + 1.0f);
}

static __device__ __forceinline__ void gload16(const void* gsrc, void* ldst) {
    __builtin_amdgcn_global_load_lds(
        (const __attribute__((address_space(1))) unsigned int*)gsrc,
        (__attribute__((address_space(3))) unsigned int*)ldst,
        16, 0, 0);
}

#define MEMFENCE asm volatile("" ::: "memory")

// ---------------- weight prep: fragment-linear bf16, 16-col gate interleave ----
__global__ void prep_weights(const float* __restrict__ Wf, const float* __restrict__ Wi,
                             const float* __restrict__ Wc, const float* __restrict__ Wo,
                             const float* __restrict__ Wch,
                             unsigned short* __restrict__ WgF,   // 512*256
                             unsigned short* __restrict__ WchF)  // 128*128
{
    int u = blockIdx.x * 256 + threadIdx.x;
    if (u < 16384) {
        int lane = u & 63, g = (u >> 6) & 3, wn = (u >> 8) & 7, ks = u >> 11;
        int l15 = lane & 15, lg = lane >> 4;
        int cg = wn * 16 + l15;
        int k0 = ks * 32 + lg * 8;
        const float* W = (g == 0) ? Wf : (g == 1) ? Wi : (g == 2) ? Wc : Wo;
        union { bf16x8 v; unsigned short s[8]; } r;
#pragma unroll
        for (int i = 0; i < 8; ++i) r.s[i] = f2bf(W[(size_t)(k0 + i) * 128 + cg]);
        *(bf16x8*)(WgF + (size_t)u * 8) = r.v;
    } else if (u < 16384 + 2048) {
        int u2 = u - 16384;
        int lane = u2 & 63, wn = (u2 >> 6) & 7, kt = u2 >> 9;
        int l15 = lane & 15, lg = lane >> 4;
        int col = wn * 16 + l15, k0 = kt * 32 + lg * 8;
        union { bf16x8 v; unsigned short s[8]; } r;
#pragma unroll
        for (int i = 0; i < 8; ++i) r.s[i] = f2bf(Wch[(size_t)(k0 + i) * 128 + col]);
        *(bf16x8*)(WchF + (size_t)u2 * 8) = r.v;
    }
}

// One 32-row tile. T may be runtime; CUR/VMC/HP are compile-time literals.
// HP=1: run GEMM2(t-1)+h-epilogue(t-1) interleaved with elementwise(t).
// OKIN/OKOUT: o-gate bf16-packed state, uint[2][2], packed via pure C++ f2bf.
#define TILE_BODY(T, CUR, OKIN, OKOUT, VMC, HP)                                 \
  do {                                                                          \
    const long m0 = base + (long)(T) * 32;                                      \
    /* c-DMA(t+1) -> clds[CUR^1]  (2 ops) */                                    \
    if ((T) < 31) {                                                             \
      char* cd = lds + ((CUR) ? CLDS0 : CLDS1);                                 \
      gload16(cg + (m0 + 32 + (tid >> 5)) * 128 + (tid & 31) * 4, cd + tid * 16);        \
      gload16(cg + (m0 + 48 + (tid >> 5)) * 128 + (tid & 31) * 4, cd + 8192 + tid * 16); \
    }                                                                           \
    MEMFENCE;                                                                   \
    /* A-DMA(t+2) -> land[CUR]  (4 ops; dummy reload at T==30 keeps counts) */  \
    if ((T) < 31) {                                                             \
      const long ar = ((T) < 30) ? (m0 + 64) : m0;                              \
      char* ad = lds + ((CUR) ? LAND1 : LAND0) + wn * 1024 + lane * 16;         \
      _Pragma("unroll")                                                         \
      for (int j = 0; j < 4; ++j)                                               \
        gload16(dmaA + (ar + wn + j * 8) * 128, ad + j * 8192);                 \
    }                                                                           \
    MEMFENCE;                                                                   \
    /* GEMM1(t): A bf16 frags from abuf[CUR], B from Breg */                    \
    {                                                                           \
      const char* ab = lds + ((CUR) ? AB1 : AB0);                               \
      _Pragma("unroll")                                                         \
      for (int ks = 0; ks < 8; ++ks) {                                          \
        bf16x8 af0 = *(const bf16x8*)(ab + ks * 1024 + ((lane * 16) ^ (ks << 4)));       \
        bf16x8 af1 = *(const bf16x8*)(ab + (8 + ks) * 1024 + ((lane * 16) ^ (ks << 4))); \
        _Pragma("unroll")                                                       \
        for (int g_ = 0; g_ < 4; ++g_) {                                        \
          acc[0][g_] = __builtin_amdgcn_mfma_f32_16x16x32_bf16(af0, Breg[ks][g_], acc[0][g_], 0, 0, 0); \
          acc[1][g_] = __builtin_amdgcn_mfma_f32_16x16x32_bf16(af1, Breg[ks][g_], acc[1][g_], 0, 0, 0); \
        }                                                                       \
      }                                                                         \
    }                                                                           \
    /* merged region: GEMM2(t-1) MFMA || elementwise(t) VALU || h-ep(t-1) */    \
    {                                                                           \
      f32x4 acc2_0 = {0.f,0.f,0.f,0.f}, acc2_1 = {0.f,0.f,0.f,0.f};             \
      if (HP) {                                                                 \
        const char* cexr = lds + ((CUR) ? CEX0 : CEX1);                         \
        _Pragma("unroll")                                                       \
        for (int kt = 0; kt < 4; ++kt) {                                        \
          bf16x8 p0 = *(const bf16x8*)(cexr + kt * 1024 + lane * 16);           \
          bf16x8 p1 = *(const bf16x8*)(cexr + (4 + kt) * 1024 + lane * 16);     \
          acc2_0 = __builtin_amdgcn_mfma_f32_16x16x32_bf16(p0, Wreg[kt], acc2_0, 0, 0, 0); \
          acc2_1 = __builtin_amdgcn_mfma_f32_16x16x32_bf16(p1, Wreg[kt], acc2_1, 0, 0, 0); \
        }                                                                       \
      }                                                                         \
      /* elementwise(t): c from clds[CUR]; c_new -> global + c_ex[CUR]; o->OKOUT */ \
      {                                                                         \
        char* cexb = lds + ((CUR) ? CEX1 : CEX0);                               \
        const char* cbr = lds + ((CUR) ? CLDS1 : CLDS0);                        \
        _Pragma("unroll")                                                       \
        for (int am = 0; am < 2; ++am) {                                        \
          float ov[4];                                                          \
          _Pragma("unroll")                                                     \
          for (int r = 0; r < 4; ++r) {                                         \
            float cval = *(const float*)(cbr + (am * 16 + lg * 4 + r) * 512 + colc * 4); \
            float f_  = fsig(acc[am][0][r] + bfb);                              \
            float i_  = fsig(acc[am][1][r] + bib);                              \
            float ct_ = ftanh(acc[am][2][r] + bcb);                             \
            float cv_ = f_ * cval + i_ * ct_;                                   \
            ov[r] = fsig(acc[am][3][r] + bob);                                  \
            coutp[(m0 + am * 16 + lg * 4 + r) * 128 + colc] = cv_;              \
            *(unsigned short*)(cexb + (am * 4 + (wn >> 1)) * 1024               \
                 + (cslotbase + lg * 4 + r) * 16 + (l15 & 7) * 2) = f2bf(cv_);  \
          }                                                                     \
          OKOUT[am][0] = (unsigned int)f2bf(ov[0]) | ((unsigned int)f2bf(ov[1]) << 16); \
          OKOUT[am][1] = (unsigned int)f2bf(ov[2]) | ((unsigned int)f2bf(ov[3]) << 16); \
        }                                                                       \
      }                                                                         \
      /* h-epilogue(t-1) */                                                     \
      if (HP) {                                                                 \
        _Pragma("unroll")                                                       \
        for (int r = 0; r < 4; ++r) {                                           \
          float o0 = (r & 1) ? obf_hi(OKIN[0][r >> 1]) : obf_lo(OKIN[0][r >> 1]); \
          float o1 = (r & 1) ? obf_hi(OKIN[1][r >> 1]) : obf_lo(OKIN[1][r >> 1]); \
          houtp[(m0 - 32 +      lg * 4 + r) * 128 + colc] = o0 * ftanh(acc2_0[r] + bchb); \
          houtp[(m0 - 32 + 16 + lg * 4 + r) * 128 + colc] = o1 * ftanh(acc2_1[r] + bchb); \
        }                                                                       \
      }                                                                         \
    }                                                                           \
    MEMFENCE;                                                                   \
    /* cvt-pass: land[CUR^1] (A for t+1, DMA'd a full body ago) -> abuf[CUR^1] */ \
    if ((T) < 31) {                                                             \
      const char* ln = lds + ((CUR) ? LAND0 : LAND1) + rowA * 1024;             \
      f32x4 q0 = *(const f32x4*)(ln + (((kgA * 4 + 0) ^ swzA) << 4));           \
      f32x4 q1 = *(const f32x4*)(ln + (((kgA * 4 + 1) ^ swzA) << 4));           \
      f32x4 q2 = *(const f32x4*)(ln + (((kgA * 4 + 2) ^ swzA) << 4));           \
      f32x4 q3 = *(const f32x4*)(ln + (((kgA * 4 + 3) ^ swzA) << 4));           \
      char* fb = lds + ((CUR) ? AB0 : AB1);                                     \
      *(bf16x8*)(fb + aoff0) = cvt8(q0, q1);                                    \
      *(bf16x8*)(fb + aoff1) = cvt8(q2, q3);                                    \
    }                                                                           \
    /* ONE barrier; fully fenced on both sides */                               \
    asm volatile("s_waitcnt lgkmcnt(0) vmcnt(" #VMC ")" ::: "memory");          \
    __builtin_amdgcn_sched_barrier(0);                                          \
    __builtin_amdgcn_s_barrier();                                               \
    __builtin_amdgcn_sched_barrier(0);                                          \
    _Pragma("unroll")                                                           \
    for (int am = 0; am < 2; ++am)                                              \
      _Pragma("unroll")                                                         \
      for (int g_ = 0; g_ < 4; ++g_) acc[am][g_] = (f32x4){0.f,0.f,0.f,0.f};    \
  } while (0)

// ---------------- fused kernel: 1024 rows per 512-thread block, 32-row tiles ----
__global__ __launch_bounds__(512, 2) void lstm_fused(
    const float* __restrict__ xg, const float* __restrict__ hg, const float* __restrict__ cg,
    const float* __restrict__ bfv, const float* __restrict__ biv,
    const float* __restrict__ bcv, const float* __restrict__ bov,
    const float* __restrict__ bchv,
    const unsigned short* __restrict__ WgF, const unsigned short* __restrict__ WchF,
    float* __restrict__ out, int nrows)
{
    __shared__ uint4 lds4[9216];                 // 144 KB
    char* lds = (char*)lds4;

    const int tid  = threadIdx.x;
    const int lane = tid & 63;
    const int wn   = tid >> 6;                   // wave id = col-group = A-row class (mod 8)
    const int l15  = lane & 15;
    const int lg   = lane >> 4;
    const long base = (long)blockIdx.x << 10;    // 1024 rows per block

    float* houtp = out;
    float* coutp = out + (size_t)nrows * 128;

    const int colc = wn * 16 + l15;              // lane-local output column
    const float bfb = bfv[colc], bib = biv[colc], bcb = bcv[colc],
                bob = bov[colc], bchb = bchv[colc];
    const int cslotbase = ((wn & 1) * 2 + (l15 >> 3)) * 16;

    // ---- weights into registers (L2-resident source; read once per block)
    bf16x8 Breg[8][4];                           // [ks][gate] : 128 VGPRs
#pragma unroll
    for (int ks = 0; ks < 8; ++ks)
#pragma unroll
        for (int g = 0; g < 4; ++g)
            Breg[ks][g] = *(const bf16x8*)(WgF + (size_t)((ks * 32 + wn * 4 + g) * 512 + lane * 8));
    bf16x8 Wreg[4];                              // [kt] : 16 VGPRs
#pragma unroll
    for (int kt = 0; kt < 4; ++kt)
        Wreg[kt] = *(const bf16x8*)(WchF + (size_t)((kt * 8 + wn) * 512 + lane * 8));

    // ---- A-DMA source: lane stages 16B unit gu = lane ^ wn of each row
    const int gu = lane ^ wn;
    const float* dmaA = ((gu < 32) ? (xg + gu * 4) : (hg + (gu - 32) * 4));

    // ---- cvt-pass thread coords (thread converts 16 k-elems of one row)
    const int rowA = tid >> 4;                   // 0..31
    const int kgA  = tid & 15;                   // 16-elem k-group
    const int swzA = rowA & 7;
    const int ksA  = kgA >> 1;
    const int lgA  = (kgA & 1) * 2;
    const int amA  = rowA >> 4;
    const int l15A = rowA & 15;
    const int aoff0 = (amA * 8 + ksA) * 1024 + ((((lgA    ) * 16 + l15A) * 16) ^ (ksA << 4));
    const int aoff1 = (amA * 8 + ksA) * 1024 + ((((lgA + 1) * 16 + l15A) * 16) ^ (ksA << 4));
    const float* asrc = (kgA < 8) ? (xg + kgA * 16) : (hg + (kgA - 8) * 16);

    // ---- prologue: c(0) DMA -> clds0; A(1) DMA -> land1; A(0) direct -> abuf0
    gload16(cg + (base + (tid >> 5)) * 128 + (tid & 31) * 4, lds + CLDS0 + tid * 16);
    gload16(cg + (base + 16 + (tid >> 5)) * 128 + (tid & 31) * 4, lds + CLDS0 + 8192 + tid * 16);
    MEMFENCE;
    {
        char* ad = lds + LAND1 + wn * 1024 + lane * 16;
#pragma unroll
        for (int j = 0; j < 4; ++j)
            gload16(dmaA + (base + 32 + wn + j * 8) * 128, ad + j * 8192);
    }
    MEMFENCE;
    {
        const float* s = asrc + (base + rowA) * 128;
        f32x4 v0 = ((const f32x4*)s)[0], v1 = ((const f32x4*)s)[1],
              v2 = ((const f32x4*)s)[2], v3 = ((const f32x4*)s)[3];
        *(bf16x8*)(lds + AB0 + aoff0) = cvt8(v0, v1);
        *(bf16x8*)(lds + AB0 + aoff1) = cvt8(v2, v3);
    }
    asm volatile("s_waitcnt lgkmcnt(0) vmcnt(0)" ::: "memory");
    __builtin_amdgcn_sched_barrier(0);
    __builtin_amdgcn_s_barrier();
    __builtin_amdgcn_sched_barrier(0);

    f32x4 acc[2][4];                             // [am][gate]
#pragma unroll
    for (int am = 0; am < 2; ++am)
#pragma unroll
        for (int g = 0; g < 4; ++g) acc[am][g] = {0.f, 0.f, 0.f, 0.f};

    unsigned int ok0[2][2], ok1[2][2];           // o-gate bf16-packed ping-pong
    ok0[0][0] = ok0[0][1] = ok0[1][0] = ok0[1][1] = 0;
    ok1[0][0] = ok1[0][1] = ok1[1][0] = ok1[1][1] = 0;

    // body 0 (peeled; no previous tile; barrier retires the 6 DMAs)
    TILE_BODY(0, 0, ok1, ok0, 8, 0);

#pragma unroll 1
    for (int t = 1; t < 31; t += 2) {
        TILE_BODY(t,     1, ok0, ok1, 16, 1);
        TILE_BODY(t + 1, 0, ok1, ok0, 16, 1);
    }

    // body 31
    TILE_BODY(31, 1, ok0, ok1, 16, 1);

    // tail: GEMM2(31) + h-epilogue(31)
    {
        const char* cexr = lds + CEX1;
        f32x4 acc2_0 = {0.f,0.f,0.f,0.f}, acc2_1 = {0.f,0.f,0.f,0.f};
#pragma unroll
        for (int kt = 0; kt < 4; ++kt) {
            bf16x8 p0 = *(const bf16x8*)(cexr + kt * 1024 + lane * 16);
            bf16x8 p1 = *(const bf16x8*)(cexr + (4 + kt) * 1024 + lane * 16);
            acc2_0 = __builtin_amdgcn_mfma_f32_16x16x32_bf16(p0, Wreg[kt], acc2_0, 0, 0, 0);
            acc2_1 = __builtin_amdgcn_mfma_f32_16x16x32_bf16(p1, Wreg[kt], acc2_1, 0, 0, 0);
        }
        const long mL = base + 31 * 32;
#pragma unroll
        for (int r = 0; r < 4; ++r) {
            float o0 = (r & 1) ? obf_hi(ok1[0][r >> 1]) : obf_lo(ok1[0][r >> 1]);
            float o1 = (r & 1) ? obf_hi(ok1[1][r >> 1]) : obf_lo(ok1[1][r >> 1]);
            houtp[(mL +      lg * 4 + r) * 128 + colc] = o0 * ftanh(acc2_0[r] + bchb);
            houtp[(mL + 16 + lg * 4 + r) * 128 + colc] = o1 * ftanh(acc2_1[r] + bchb);
        }
    }
}

extern "C" void kernel_launch(void* const* d_in, const int* in_sizes, int n_in,
                              void* d_out, int out_size, void* d_ws, size_t ws_size,
                              hipStream_t stream)
{
    const float* x   = (const float*)d_in[0];
    const float* h   = (const float*)d_in[1];
    const float* c   = (const float*)d_in[2];
    const float* Wf  = (const float*)d_in[3];
    const float* bf_ = (const float*)d_in[4];
    const float* Wi  = (const float*)d_in[5];
    const float* bi_ = (const float*)d_in[6];
    const float* Wc  = (const float*)d_in[7];
    const float* bc_ = (const float*)d_in[8];
    const float* Wo  = (const float*)d_in[9];
    const float* bo_ = (const float*)d_in[10];
    const float* Wch = (const float*)d_in[11];
    const float* bch = (const float*)d_in[12];

    unsigned short* WgF  = (unsigned short*)d_ws;         // 512*256 bf16 fragment-linear
    unsigned short* WchF = WgF + 512 * 256;               // 128*128 bf16 fragment-linear
    float* out = (float*)d_out;

    int nrows = in_sizes[0] / 128;                        // 262144

    prep_weights<<<dim3(72), dim3(256), 0, stream>>>(Wf, Wi, Wc, Wo, Wch, WgF, WchF);
    lstm_fused<<<dim3(nrows / 1024), dim3(512), 0, stream>>>(
        x, h, c, bf_, bi_, bc_, bo_, bch, WgF, WchF, out, nrows);
}

// Round 16
// 145.497 us; speedup vs baseline: 1.7350x; 1.7350x over previous
//
#include <hip/hip_runtime.h>
#include <hip/hip_bf16.h>

// LSTM block, fused. Inputs fp32, outputs fp32. bf16 MFMA internally.
// Consolidation of the two best proven kernels:
//   r12 A-path: A(t+2) via global_load_lds DMA -> fp32 land dbuf (zero regs),
//               shared cvt-pass -> bf16 frag abuf one tile later.
//   r7  c-path: c input in registers, ping-pong c0/c1 loaded one tile ahead.
// Weights in regs (Breg 128/wave + Wreg 16, gate-interleaved -> elementwise
// lane-local). ONE barrier per 32-row tile, lgkmcnt(0)-ONLY (no vmcnt: stores
// and DMAs stay in flight across barriers). cvt-pass guarded by exact
// vmcnt(36) (ops newer than A(t+1) in the FIFO). Dummy A-DMA at T==30 keeps
// counts uniform. sched_barrier(0) on both sides of every s_barrier.
// LDS 112K: abuf bf16 2x16K | land fp32 2x32K | c_ex 2x8K.

typedef __attribute__((ext_vector_type(8))) short bf16x8;   // 8 bf16 = 4 VGPRs
typedef __attribute__((ext_vector_type(4))) float f32x4;

#define AB0   0
#define AB1   16384
#define LAND0 32768
#define LAND1 65536
#define CEX0  98304
#define CEX1  106496

static __device__ __forceinline__ unsigned short f2bf(float f) {
    unsigned int u = __builtin_bit_cast(unsigned int, f);
    u += 0x7FFFu + ((u >> 16) & 1u);      // RNE
    return (unsigned short)(u >> 16);
}

static __device__ __forceinline__ unsigned int cvtpk(float lo, float hi) {
    unsigned int r;
    asm("v_cvt_pk_bf16_f32 %0, %1, %2" : "=v"(r) : "v"(lo), "v"(hi));
    return r;
}

static __device__ __forceinline__ bf16x8 cvt8(f32x4 a, f32x4 b) {
    union { bf16x8 v; unsigned int w[4]; } r;
    r.w[0] = cvtpk(a[0], a[1]);
    r.w[1] = cvtpk(a[2], a[3]);
    r.w[2] = cvtpk(b[0], b[1]);
    r.w[3] = cvtpk(b[2], b[3]);
    return r.v;
}

static __device__ __forceinline__ float fsig(float x) {
    float e = __builtin_amdgcn_exp2f(-1.44269504f * x);
    return __builtin_amdgcn_rcpf(1.0f + e);
}
static __device__ __forceinline__ float ftanh(float x) {
    float e = __builtin_amdgcn_exp2f(2.8853900818f * x);
    return 1.0f - 2.0f * __builtin_amdgcn_rcpf(e + 1.0f);
}

static __device__ __forceinline__ void gload16(const void* gsrc, void* ldst) {
    __builtin_amdgcn_global_load_lds(
        (const __attribute__((address_space(1))) unsigned int*)gsrc,
        (__attribute__((address_space(3))) unsigned int*)ldst,
        16, 0, 0);
}

#define MEMFENCE asm volatile("" ::: "memory")

// ---------------- weight prep: fragment-linear bf16, 16-col gate interleave ----
__global__ void prep_weights(const float* __restrict__ Wf, const float* __restrict__ Wi,
                             const float* __restrict__ Wc, const float* __restrict__ Wo,
                             const float* __restrict__ Wch,
                             unsigned short* __restrict__ WgF,   // 512*256
                             unsigned short* __restrict__ WchF)  // 128*128
{
    int u = blockIdx.x * 256 + threadIdx.x;
    if (u < 16384) {
        int lane = u & 63, g = (u >> 6) & 3, wn = (u >> 8) & 7, ks = u >> 11;
        int l15 = lane & 15, lg = lane >> 4;
        int cg = wn * 16 + l15;
        int k0 = ks * 32 + lg * 8;
        const float* W = (g == 0) ? Wf : (g == 1) ? Wi : (g == 2) ? Wc : Wo;
        union { bf16x8 v; unsigned short s[8]; } r;
#pragma unroll
        for (int i = 0; i < 8; ++i) r.s[i] = f2bf(W[(size_t)(k0 + i) * 128 + cg]);
        *(bf16x8*)(WgF + (size_t)u * 8) = r.v;
    } else if (u < 16384 + 2048) {
        int u2 = u - 16384;
        int lane = u2 & 63, wn = (u2 >> 6) & 7, kt = u2 >> 9;
        int l15 = lane & 15, lg = lane >> 4;
        int col = wn * 16 + l15, k0 = kt * 32 + lg * 8;
        union { bf16x8 v; unsigned short s[8]; } r;
#pragma unroll
        for (int i = 0; i < 8; ++i) r.s[i] = f2bf(Wch[(size_t)(k0 + i) * 128 + col]);
        *(bf16x8*)(WchF + (size_t)u2 * 8) = r.v;
    }
}

// One 32-row tile. CUR = compile-time parity (t & 1).
// CIN = c-input regs for tile T (loaded last body); COUT receives c(T+1).
#define TILE_BODY(T, CUR, CIN, COUT)                                            \
  do {                                                                          \
    const long m0 = base + (long)(T) * 32;                                      \
    /* c-loads(t+1) -> COUT regs (8 scalar loads, first vm ops of the body) */  \
    if ((T) < 31) {                                                             \
      _Pragma("unroll")                                                         \
      for (int am = 0; am < 2; ++am)                                            \
        _Pragma("unroll")                                                       \
        for (int r = 0; r < 4; ++r)                                             \
          COUT[am * 4 + r] = cg[(m0 + 32 + am * 16 + lg * 4 + r) * 128 + colc]; \
    }                                                                           \
    MEMFENCE;                                                                   \
    /* A-DMA(t+2) -> land[CUR]  (4 ops; dummy reload at T==30 keeps counts) */  \
    if ((T) < 31) {                                                             \
      const long ar = ((T) < 30) ? (m0 + 64) : m0;                              \
      char* ad = lds + ((CUR) ? LAND1 : LAND0) + wn * 1024 + lane * 16;         \
      _Pragma("unroll")                                                         \
      for (int j = 0; j < 4; ++j)                                               \
        gload16(dmaA + (ar + wn + j * 8) * 128, ad + j * 8192);                 \
    }                                                                           \
    MEMFENCE;                                                                   \
    /* GEMM1(t): A bf16 frags from abuf[CUR], B from Breg */                    \
    {                                                                           \
      const char* ab = lds + ((CUR) ? AB1 : AB0);                               \
      _Pragma("unroll")                                                         \
      for (int ks = 0; ks < 8; ++ks) {                                          \
        bf16x8 af0 = *(const bf16x8*)(ab + ks * 1024 + ((lane * 16) ^ (ks << 4)));       \
        bf16x8 af1 = *(const bf16x8*)(ab + (8 + ks) * 1024 + ((lane * 16) ^ (ks << 4))); \
        _Pragma("unroll")                                                       \
        for (int g_ = 0; g_ < 4; ++g_) {                                        \
          acc[0][g_] = __builtin_amdgcn_mfma_f32_16x16x32_bf16(af0, Breg[ks][g_], acc[0][g_], 0, 0, 0); \
          acc[1][g_] = __builtin_amdgcn_mfma_f32_16x16x32_bf16(af1, Breg[ks][g_], acc[1][g_], 0, 0, 0); \
        }                                                                       \
      }                                                                         \
    }                                                                           \
    /* elementwise(t): c from CIN regs; c_new -> global + c_ex[CUR] */          \
    {                                                                           \
      char* cexb = lds + ((CUR) ? CEX1 : CEX0);                                 \
      _Pragma("unroll")                                                         \
      for (int am = 0; am < 2; ++am)                                            \
        _Pragma("unroll")                                                       \
        for (int r = 0; r < 4; ++r) {                                           \
          float f_  = fsig(acc[am][0][r] + bfb);                                \
          float i_  = fsig(acc[am][1][r] + bib);                                \
          float ct_ = ftanh(acc[am][2][r] + bcb);                               \
          float cv_ = f_ * CIN[am * 4 + r] + i_ * ct_;                          \
          coutp[(m0 + am * 16 + lg * 4 + r) * 128 + colc] = cv_;                \
          *(unsigned short*)(cexb + (am * 4 + (wn >> 1)) * 1024                 \
               + (cslotbase + lg * 4 + r) * 16 + (l15 & 7) * 2) = f2bf(cv_);    \
        }                                                                       \
    }                                                                           \
    MEMFENCE;                                                                   \
    /* cvt-pass: land[CUR^1] (A for t+1, DMA'd a full body ago) -> abuf[CUR^1]  \
       exact guard: 36 vm ops are newer than the A(t+1) DMA group */            \
    if ((T) < 31) {                                                             \
      asm volatile("s_waitcnt vmcnt(36)" ::: "memory");                         \
      const char* ln = lds + ((CUR) ? LAND0 : LAND1) + rowA * 1024;             \
      f32x4 q0 = *(const f32x4*)(ln + (((kgA * 4 + 0) ^ swzA) << 4));           \
      f32x4 q1 = *(const f32x4*)(ln + (((kgA * 4 + 1) ^ swzA) << 4));           \
      f32x4 q2 = *(const f32x4*)(ln + (((kgA * 4 + 2) ^ swzA) << 4));           \
      f32x4 q3 = *(const f32x4*)(ln + (((kgA * 4 + 3) ^ swzA) << 4));           \
      char* fb = lds + ((CUR) ? AB0 : AB1);                                     \
      *(bf16x8*)(fb + aoff0) = cvt8(q0, q1);                                    \
      *(bf16x8*)(fb + aoff1) = cvt8(q2, q3);                                    \
    }                                                                           \
    /* ONE barrier: lgkm-only (no vmcnt -- stores/DMAs stay in flight) */       \
    asm volatile("s_waitcnt lgkmcnt(0)" ::: "memory");                          \
    __builtin_amdgcn_sched_barrier(0);                                          \
    __builtin_amdgcn_s_barrier();                                               \
    __builtin_amdgcn_sched_barrier(0);                                          \
    /* GEMM2(t) (c_ex[CUR] x Wreg) + h epilogue */                              \
    {                                                                           \
      const char* cexr = lds + ((CUR) ? CEX1 : CEX0);                           \
      f32x4 acc2_0 = {0.f,0.f,0.f,0.f}, acc2_1 = {0.f,0.f,0.f,0.f};             \
      _Pragma("unroll")                                                         \
      for (int kt = 0; kt < 4; ++kt) {                                          \
        bf16x8 p0 = *(const bf16x8*)(cexr + kt * 1024 + lane * 16);             \
        bf16x8 p1 = *(const bf16x8*)(cexr + (4 + kt) * 1024 + lane * 16);       \
        acc2_0 = __builtin_amdgcn_mfma_f32_16x16x32_bf16(p0, Wreg[kt], acc2_0, 0, 0, 0); \
        acc2_1 = __builtin_amdgcn_mfma_f32_16x16x32_bf16(p1, Wreg[kt], acc2_1, 0, 0, 0); \
      }                                                                         \
      _Pragma("unroll")                                                         \
      for (int r = 0; r < 4; ++r) {                                             \
        float o0 = fsig(acc[0][3][r] + bob);                                    \
        houtp[(m0 +      lg * 4 + r) * 128 + colc] = o0 * ftanh(acc2_0[r] + bchb); \
        float o1 = fsig(acc[1][3][r] + bob);                                    \
        houtp[(m0 + 16 + lg * 4 + r) * 128 + colc] = o1 * ftanh(acc2_1[r] + bchb); \
      }                                                                         \
    }                                                                           \
    _Pragma("unroll")                                                           \
    for (int am = 0; am < 2; ++am)                                              \
      _Pragma("unroll")                                                         \
      for (int g_ = 0; g_ < 4; ++g_) acc[am][g_] = (f32x4){0.f,0.f,0.f,0.f};    \
  } while (0)

// ---------------- fused kernel: 1024 rows per 512-thread block, 32-row tiles ----
__global__ __launch_bounds__(512, 2) void lstm_fused(
    const float* __restrict__ xg, const float* __restrict__ hg, const float* __restrict__ cg,
    const float* __restrict__ bfv, const float* __restrict__ biv,
    const float* __restrict__ bcv, const float* __restrict__ bov,
    const float* __restrict__ bchv,
    const unsigned short* __restrict__ WgF, const unsigned short* __restrict__ WchF,
    float* __restrict__ out, int nrows)
{
    __shared__ uint4 lds4[7168];                 // 112 KB
    char* lds = (char*)lds4;

    const int tid  = threadIdx.x;
    const int lane = tid & 63;
    const int wn   = tid >> 6;                   // wave id = col-group = A-row class (mod 8)
    const int l15  = lane & 15;
    const int lg   = lane >> 4;
    const long base = (long)blockIdx.x << 10;    // 1024 rows per block

    float* houtp = out;
    float* coutp = out + (size_t)nrows * 128;

    const int colc = wn * 16 + l15;              // lane-local output column
    const float bfb = bfv[colc], bib = biv[colc], bcb = bcv[colc],
                bob = bov[colc], bchb = bchv[colc];
    const int cslotbase = ((wn & 1) * 2 + (l15 >> 3)) * 16;

    // ---- weights into registers (L2-resident source; read once per block)
    bf16x8 Breg[8][4];                           // [ks][gate] : 128 VGPRs
#pragma unroll
    for (int ks = 0; ks < 8; ++ks)
#pragma unroll
        for (int g = 0; g < 4; ++g)
            Breg[ks][g] = *(const bf16x8*)(WgF + (size_t)((ks * 32 + wn * 4 + g) * 512 + lane * 8));
    bf16x8 Wreg[4];                              // [kt] : 16 VGPRs
#pragma unroll
    for (int kt = 0; kt < 4; ++kt)
        Wreg[kt] = *(const bf16x8*)(WchF + (size_t)((kt * 8 + wn) * 512 + lane * 8));

    // ---- A-DMA source: lane stages 16B unit gu = lane ^ wn of each row
    //      LDS[row][u] = G[row][u ^ (row&7)]; rows wn+8j (row&7 == wn)
    const int gu = lane ^ wn;
    const float* dmaA = ((gu < 32) ? (xg + gu * 4) : (hg + (gu - 32) * 4));

    // ---- cvt-pass thread coords (thread converts 16 k-elems of one row)
    const int rowA = tid >> 4;                   // 0..31
    const int kgA  = tid & 15;                   // 16-elem k-group
    const int swzA = rowA & 7;
    const int ksA  = kgA >> 1;
    const int lgA  = (kgA & 1) * 2;
    const int amA  = rowA >> 4;
    const int l15A = rowA & 15;
    const int aoff0 = (amA * 8 + ksA) * 1024 + ((((lgA    ) * 16 + l15A) * 16) ^ (ksA << 4));
    const int aoff1 = (amA * 8 + ksA) * 1024 + ((((lgA + 1) * 16 + l15A) * 16) ^ (ksA << 4));
    const float* asrc = (kgA < 8) ? (xg + kgA * 16) : (hg + (kgA - 8) * 16);

    // ---- prologue: c(0) -> c0 regs; A(1) DMA -> land1; A(0) direct -> abuf0
    float c0[8], c1[8];
#pragma unroll
    for (int am = 0; am < 2; ++am)
#pragma unroll
        for (int r = 0; r < 4; ++r)
            c0[am * 4 + r] = cg[(base + am * 16 + lg * 4 + r) * 128 + colc];
    MEMFENCE;
    {
        char* ad = lds + LAND1 + wn * 1024 + lane * 16;
#pragma unroll
        for (int j = 0; j < 4; ++j)
            gload16(dmaA + (base + 32 + wn + j * 8) * 128, ad + j * 8192);
    }
    MEMFENCE;
    {
        const float* s = asrc + (base + rowA) * 128;
        f32x4 v0 = ((const f32x4*)s)[0], v1 = ((const f32x4*)s)[1],
              v2 = ((const f32x4*)s)[2], v3 = ((const f32x4*)s)[3];
        *(bf16x8*)(lds + AB0 + aoff0) = cvt8(v0, v1);
        *(bf16x8*)(lds + AB0 + aoff1) = cvt8(v2, v3);
    }
    asm volatile("s_waitcnt lgkmcnt(0) vmcnt(0)" ::: "memory");
    __builtin_amdgcn_sched_barrier(0);
    __builtin_amdgcn_s_barrier();
    __builtin_amdgcn_sched_barrier(0);

    f32x4 acc[2][4];                             // [am][gate]
#pragma unroll
    for (int am = 0; am < 2; ++am)
#pragma unroll
        for (int g = 0; g < 4; ++g) acc[am][g] = {0.f, 0.f, 0.f, 0.f};

#pragma unroll 1
    for (int t = 0; t < 32; t += 2) {
        TILE_BODY(t,     0, c0, c1);
        TILE_BODY(t + 1, 1, c1, c0);
    }
}

extern "C" void kernel_launch(void* const* d_in, const int* in_sizes, int n_in,
                              void* d_out, int out_size, void* d_ws, size_t ws_size,
                              hipStream_t stream)
{
    const float* x   = (const float*)d_in[0];
    const float* h   = (const float*)d_in[1];
    const float* c   = (const float*)d_in[2];
    const float* Wf  = (const float*)d_in[3];
    const float* bf_ = (const float*)d_in[4];
    const float* Wi  = (const float*)d_in[5];
    const float* bi_ = (const float*)d_in[6];
    const float* Wc  = (const float*)d_in[7];
    const float* bc_ = (const float*)d_in[8];
    const float* Wo  = (const float*)d_in[9];
    const float* bo_ = (const float*)d_in[10];
    const float* Wch = (const float*)d_in[11];
    const float* bch = (const float*)d_in[12];

    unsigned short* WgF  = (unsigned short*)d_ws;         // 512*256 bf16 fragment-linear
    unsigned short* WchF = WgF + 512 * 256;               // 128*128 bf16 fragment-linear
    float* out = (float*)d_out;

    int nrows = in_sizes[0] / 128;                        // 262144

    prep_weights<<<dim3(72), dim3(256), 0, stream>>>(Wf, Wi, Wc, Wo, Wch, WgF, WchF);
    lstm_fused<<<dim3(nrows / 1024), dim3(512), 0, stream>>>(
        x, h, c, bf_, bi_, bc_, bo_, bch, WgF, WchF, out, nrows);
}

// Round 18
// 142.650 us; speedup vs baseline: 1.7697x; 1.0200x over previous
//
#include <hip/hip_runtime.h>
#include <hip/hip_bf16.h>

// LSTM block, fused. Inputs fp32, outputs fp32. bf16 MFMA internally.
// r17 schedule (cvt-pass at body top; post-barrier region = GEMM2(t-1) ||
// h-ep(t-1) || cvt(t) || c-loads || A-DMA || GEMM1(t)) with AIRTIGHT sync:
// the per-tile barrier waits lgkmcnt(0) vmcnt(8), retiring every wave's
// A-DMA before the barrier publishes it (global_load_lds completion is only
// visible via the ISSUING wave's vmcnt -- r17's cross-wave race, fixed).
// Weights in regs (Breg 128/wave + Wreg 16, gate-interleaved). ONE barrier
// per 32-row tile. LDS 112K: abuf 2x16K | land 2x32K | cex 2x8K.

typedef __attribute__((ext_vector_type(8))) short bf16x8;   // 8 bf16 = 4 VGPRs
typedef __attribute__((ext_vector_type(4))) float f32x4;

#define AB0   0
#define AB1   16384
#define LAND0 32768
#define LAND1 65536
#define CEX0  98304
#define CEX1  106496

static __device__ __forceinline__ unsigned short f2bf(float f) {
    unsigned int u = __builtin_bit_cast(unsigned int, f);
    u += 0x7FFFu + ((u >> 16) & 1u);      // RNE
    return (unsigned short)(u >> 16);
}

static __device__ __forceinline__ unsigned int cvtpk(float lo, float hi) {
    unsigned int r;
    asm("v_cvt_pk_bf16_f32 %0, %1, %2" : "=v"(r) : "v"(lo), "v"(hi));
    return r;
}

static __device__ __forceinline__ bf16x8 cvt8(f32x4 a, f32x4 b) {
    union { bf16x8 v; unsigned int w[4]; } r;
    r.w[0] = cvtpk(a[0], a[1]);
    r.w[1] = cvtpk(a[2], a[3]);
    r.w[2] = cvtpk(b[0], b[1]);
    r.w[3] = cvtpk(b[2], b[3]);
    return r.v;
}

static __device__ __forceinline__ float fsig(float x) {
    float e = __builtin_amdgcn_exp2f(-1.44269504f * x);
    return __builtin_amdgcn_rcpf(1.0f + e);
}
static __device__ __forceinline__ float ftanh(float x) {
    float e = __builtin_amdgcn_exp2f(2.8853900818f * x);
    return 1.0f - 2.0f * __builtin_amdgcn_rcpf(e + 1.0f);
}

static __device__ __forceinline__ void gload16(const void* gsrc, void* ldst) {
    __builtin_amdgcn_global_load_lds(
        (const __attribute__((address_space(1))) unsigned int*)gsrc,
        (__attribute__((address_space(3))) unsigned int*)ldst,
        16, 0, 0);
}

#define MEMFENCE asm volatile("" ::: "memory")

// ---------------- weight prep: fragment-linear bf16, 16-col gate interleave ----
__global__ void prep_weights(const float* __restrict__ Wf, const float* __restrict__ Wi,
                             const float* __restrict__ Wc, const float* __restrict__ Wo,
                             const float* __restrict__ Wch,
                             unsigned short* __restrict__ WgF,   // 512*256
                             unsigned short* __restrict__ WchF)  // 128*128
{
    int u = blockIdx.x * 256 + threadIdx.x;
    if (u < 16384) {
        int lane = u & 63, g = (u >> 6) & 3, wn = (u >> 8) & 7, ks = u >> 11;
        int l15 = lane & 15, lg = lane >> 4;
        int cg = wn * 16 + l15;
        int k0 = ks * 32 + lg * 8;
        const float* W = (g == 0) ? Wf : (g == 1) ? Wi : (g == 2) ? Wc : Wo;
        union { bf16x8 v; unsigned short s[8]; } r;
#pragma unroll
        for (int i = 0; i < 8; ++i) r.s[i] = f2bf(W[(size_t)(k0 + i) * 128 + cg]);
        *(bf16x8*)(WgF + (size_t)u * 8) = r.v;
    } else if (u < 16384 + 2048) {
        int u2 = u - 16384;
        int lane = u2 & 63, wn = (u2 >> 6) & 7, kt = u2 >> 9;
        int l15 = lane & 15, lg = lane >> 4;
        int col = wn * 16 + l15, k0 = kt * 32 + lg * 8;
        union { bf16x8 v; unsigned short s[8]; } r;
#pragma unroll
        for (int i = 0; i < 8; ++i) r.s[i] = f2bf(Wch[(size_t)(k0 + i) * 128 + col]);
        *(bf16x8*)(WchF + (size_t)u2 * 8) = r.v;
    }
}

// One 32-row tile. CUR = compile-time parity (t & 1).
// CIN = c-input regs for tile T (loaded last body); COUT receives c(T+1).
#define TILE_BODY(T, CUR, CIN, COUT)                                            \
  do {                                                                          \
    const long m0 = base + (long)(T) * 32;                                      \
    /* cvt-pass AT BODY TOP: land[CUR^1] (A(T+1)) -> abuf[CUR^1].               \
       NO guard needed: previous barrier's vmcnt(8) retired every wave's       \
       A(T+1) DMA before publishing. */                                         \
    if ((T) < 31) {                                                             \
      const char* ln = lds + ((CUR) ? LAND0 : LAND1) + rowA * 1024;             \
      f32x4 q0 = *(const f32x4*)(ln + (((kgA * 4 + 0) ^ swzA) << 4));           \
      f32x4 q1 = *(const f32x4*)(ln + (((kgA * 4 + 1) ^ swzA) << 4));           \
      f32x4 q2 = *(const f32x4*)(ln + (((kgA * 4 + 2) ^ swzA) << 4));           \
      f32x4 q3 = *(const f32x4*)(ln + (((kgA * 4 + 3) ^ swzA) << 4));           \
      char* fb = lds + ((CUR) ? AB0 : AB1);                                     \
      *(bf16x8*)(fb + aoff0) = cvt8(q0, q1);                                    \
      *(bf16x8*)(fb + aoff1) = cvt8(q2, q3);                                    \
    }                                                                           \
    MEMFENCE;                                                                   \
    /* c-loads(t+1) -> COUT regs (8 scalar loads) */                            \
    if ((T) < 31) {                                                             \
      _Pragma("unroll")                                                         \
      for (int am = 0; am < 2; ++am)                                            \
        _Pragma("unroll")                                                       \
        for (int r = 0; r < 4; ++r)                                             \
          COUT[am * 4 + r] = cg[(m0 + 32 + am * 16 + lg * 4 + r) * 128 + colc]; \
    }                                                                           \
    MEMFENCE;                                                                   \
    /* A-DMA(t+2) -> land[CUR]  (4 ops) */                                      \
    if ((T) < 30) {                                                             \
      char* ad = lds + ((CUR) ? LAND1 : LAND0) + wn * 1024 + lane * 16;         \
      _Pragma("unroll")                                                         \
      for (int j = 0; j < 4; ++j)                                               \
        gload16(dmaA + (m0 + 64 + wn + j * 8) * 128, ad + j * 8192);            \
    }                                                                           \
    MEMFENCE;                                                                   \
    /* GEMM1(t): A bf16 frags from abuf[CUR], B from Breg */                    \
    {                                                                           \
      const char* ab = lds + ((CUR) ? AB1 : AB0);                               \
      _Pragma("unroll")                                                         \
      for (int ks = 0; ks < 8; ++ks) {                                          \
        bf16x8 af0 = *(const bf16x8*)(ab + ks * 1024 + ((lane * 16) ^ (ks << 4)));       \
        bf16x8 af1 = *(const bf16x8*)(ab + (8 + ks) * 1024 + ((lane * 16) ^ (ks << 4))); \
        _Pragma("unroll")                                                       \
        for (int g_ = 0; g_ < 4; ++g_) {                                        \
          acc[0][g_] = __builtin_amdgcn_mfma_f32_16x16x32_bf16(af0, Breg[ks][g_], acc[0][g_], 0, 0, 0); \
          acc[1][g_] = __builtin_amdgcn_mfma_f32_16x16x32_bf16(af1, Breg[ks][g_], acc[1][g_], 0, 0, 0); \
        }                                                                       \
      }                                                                         \
    }                                                                           \
    /* elementwise(t): c from CIN regs; c_new -> global + c_ex[CUR] */          \
    {                                                                           \
      char* cexb = lds + ((CUR) ? CEX1 : CEX0);                                 \
      _Pragma("unroll")                                                         \
      for (int am = 0; am < 2; ++am)                                            \
        _Pragma("unroll")                                                       \
        for (int r = 0; r < 4; ++r) {                                           \
          float f_  = fsig(acc[am][0][r] + bfb);                                \
          float i_  = fsig(acc[am][1][r] + bib);                                \
          float ct_ = ftanh(acc[am][2][r] + bcb);                               \
          float cv_ = f_ * CIN[am * 4 + r] + i_ * ct_;                          \
          coutp[(m0 + am * 16 + lg * 4 + r) * 128 + colc] = cv_;                \
          *(unsigned short*)(cexb + (am * 4 + (wn >> 1)) * 1024                 \
               + (cslotbase + lg * 4 + r) * 16 + (l15 & 7) * 2) = f2bf(cv_);    \
        }                                                                       \
    }                                                                           \
    /* ONE barrier: lgkmcnt(0) + vmcnt(8). vmcnt(8) leaves only this body's    \
       8 c-stores in flight -- A-DMA (4 ops older) is RETIRED, so the barrier  \
       publishes land[] to all waves. h-stores/c-loads also retired (old). */   \
    asm volatile("s_waitcnt lgkmcnt(0) vmcnt(8)" ::: "memory");                 \
    __builtin_amdgcn_sched_barrier(0);                                          \
    __builtin_amdgcn_s_barrier();                                               \
    __builtin_amdgcn_sched_barrier(0);                                          \
    /* GEMM2(t) (c_ex[CUR] x Wreg) + h epilogue */                              \
    {                                                                           \
      const char* cexr = lds + ((CUR) ? CEX1 : CEX0);                           \
      f32x4 acc2_0 = {0.f,0.f,0.f,0.f}, acc2_1 = {0.f,0.f,0.f,0.f};             \
      _Pragma("unroll")                                                         \
      for (int kt = 0; kt < 4; ++kt) {                                          \
        bf16x8 p0 = *(const bf16x8*)(cexr + kt * 1024 + lane * 16);             \
        bf16x8 p1 = *(const bf16x8*)(cexr + (4 + kt) * 1024 + lane * 16);       \
        acc2_0 = __builtin_amdgcn_mfma_f32_16x16x32_bf16(p0, Wreg[kt], acc2_0, 0, 0, 0); \
        acc2_1 = __builtin_amdgcn_mfma_f32_16x16x32_bf16(p1, Wreg[kt], acc2_1, 0, 0, 0); \
      }                                                                         \
      _Pragma("unroll")                                                         \
      for (int r = 0; r < 4; ++r) {                                             \
        float o0 = fsig(acc[0][3][r] + bob);                                    \
        houtp[(m0 +      lg * 4 + r) * 128 + colc] = o0 * ftanh(acc2_0[r] + bchb); \
        float o1 = fsig(acc[1][3][r] + bob);                                    \
        houtp[(m0 + 16 + lg * 4 + r) * 128 + colc] = o1 * ftanh(acc2_1[r] + bchb); \
      }                                                                         \
    }                                                                           \
    _Pragma("unroll")                                                           \
    for (int am = 0; am < 2; ++am)                                              \
      _Pragma("unroll")                                                         \
      for (int g_ = 0; g_ < 4; ++g_) acc[am][g_] = (f32x4){0.f,0.f,0.f,0.f};    \
  } while (0)

// ---------------- fused kernel: 1024 rows per 512-thread block, 32-row tiles ----
__global__ __launch_bounds__(512, 2) void lstm_fused(
    const float* __restrict__ xg, const float* __restrict__ hg, const float* __restrict__ cg,
    const float* __restrict__ bfv, const float* __restrict__ biv,
    const float* __restrict__ bcv, const float* __restrict__ bov,
    const float* __restrict__ bchv,
    const unsigned short* __restrict__ WgF, const unsigned short* __restrict__ WchF,
    float* __restrict__ out, int nrows)
{
    __shared__ uint4 lds4[7168];                 // 112 KB
    char* lds = (char*)lds4;

    const int tid  = threadIdx.x;
    const int lane = tid & 63;
    const int wn   = tid >> 6;                   // wave id = col-group = A-row class (mod 8)
    const int l15  = lane & 15;
    const int lg   = lane >> 4;
    const long base = (long)blockIdx.x << 10;    // 1024 rows per block

    float* houtp = out;
    float* coutp = out + (size_t)nrows * 128;

    const int colc = wn * 16 + l15;              // lane-local output column
    const float bfb = bfv[colc], bib = biv[colc], bcb = bcv[colc],
                bob = bov[colc], bchb = bchv[colc];
    const int cslotbase = ((wn & 1) * 2 + (l15 >> 3)) * 16;

    // ---- weights into registers (L2-resident source; read once per block)
    bf16x8 Breg[8][4];                           // [ks][gate] : 128 VGPRs
#pragma unroll
    for (int ks = 0; ks < 8; ++ks)
#pragma unroll
        for (int g = 0; g < 4; ++g)
            Breg[ks][g] = *(const bf16x8*)(WgF + (size_t)((ks * 32 + wn * 4 + g) * 512 + lane * 8));
    bf16x8 Wreg[4];                              // [kt] : 16 VGPRs
#pragma unroll
    for (int kt = 0; kt < 4; ++kt)
        Wreg[kt] = *(const bf16x8*)(WchF + (size_t)((kt * 8 + wn) * 512 + lane * 8));

    // ---- A-DMA source: lane stages 16B unit gu = lane ^ wn of each row
    //      LDS[row][u] = G[row][u ^ (row&7)]; rows wn+8j (row&7 == wn)
    const int gu = lane ^ wn;
    const float* dmaA = ((gu < 32) ? (xg + gu * 4) : (hg + (gu - 32) * 4));

    // ---- cvt-pass thread coords (thread converts 16 k-elems of one row)
    const int rowA = tid >> 4;                   // 0..31
    const int kgA  = tid & 15;                   // 16-elem k-group
    const int swzA = rowA & 7;
    const int ksA  = kgA >> 1;
    const int lgA  = (kgA & 1) * 2;
    const int amA  = rowA >> 4;
    const int l15A = rowA & 15;
    const int aoff0 = (amA * 8 + ksA) * 1024 + ((((lgA    ) * 16 + l15A) * 16) ^ (ksA << 4));
    const int aoff1 = (amA * 8 + ksA) * 1024 + ((((lgA + 1) * 16 + l15A) * 16) ^ (ksA << 4));
    const float* asrc = (kgA < 8) ? (xg + kgA * 16) : (hg + (kgA - 8) * 16);

    // ---- prologue: c(0) -> c0 regs; A(1) DMA -> land1; A(0) direct -> abuf0
    float c0[8], c1[8];
#pragma unroll
    for (int am = 0; am < 2; ++am)
#pragma unroll
        for (int r = 0; r < 4; ++r)
            c0[am * 4 + r] = cg[(base + am * 16 + lg * 4 + r) * 128 + colc];
    MEMFENCE;
    {
        char* ad = lds + LAND1 + wn * 1024 + lane * 16;
#pragma unroll
        for (int j = 0; j < 4; ++j)
            gload16(dmaA + (base + 32 + wn + j * 8) * 128, ad + j * 8192);
    }
    MEMFENCE;
    {
        const float* s = asrc + (base + rowA) * 128;
        f32x4 v0 = ((const f32x4*)s)[0], v1 = ((const f32x4*)s)[1],
              v2 = ((const f32x4*)s)[2], v3 = ((const f32x4*)s)[3];
        *(bf16x8*)(lds + AB0 + aoff0) = cvt8(v0, v1);
        *(bf16x8*)(lds + AB0 + aoff1) = cvt8(v2, v3);
    }
    asm volatile("s_waitcnt lgkmcnt(0) vmcnt(0)" ::: "memory");
    __builtin_amdgcn_sched_barrier(0);
    __builtin_amdgcn_s_barrier();
    __builtin_amdgcn_sched_barrier(0);

    f32x4 acc[2][4];                             // [am][gate]
#pragma unroll
    for (int am = 0; am < 2; ++am)
#pragma unroll
        for (int g = 0; g < 4; ++g) acc[am][g] = {0.f, 0.f, 0.f, 0.f};

#pragma unroll 1
    for (int t = 0; t < 32; t += 2) {
        TILE_BODY(t,     0, c0, c1);
        TILE_BODY(t + 1, 1, c1, c0);
    }
}

extern "C" void kernel_launch(void* const* d_in, const int* in_sizes, int n_in,
                              void* d_out, int out_size, void* d_ws, size_t ws_size,
                              hipStream_t stream)
{
    const float* x   = (const float*)d_in[0];
    const float* h   = (const float*)d_in[1];
    const float* c   = (const float*)d_in[2];
    const float* Wf  = (const float*)d_in[3];
    const float* bf_ = (const float*)d_in[4];
    const float* Wi  = (const float*)d_in[5];
    const float* bi_ = (const float*)d_in[6];
    const float* Wc  = (const float*)d_in[7];
    const float* bc_ = (const float*)d_in[8];
    const float* Wo  = (const float*)d_in[9];
    const float* bo_ = (const float*)d_in[10];
    const float* Wch = (const float*)d_in[11];
    const float* bch = (const float*)d_in[12];

    unsigned short* WgF  = (unsigned short*)d_ws;         // 512*256 bf16 fragment-linear
    unsigned short* WchF = WgF + 512 * 256;               // 128*128 bf16 fragment-linear
    float* out = (float*)d_out;

    int nrows = in_sizes[0] / 128;                        // 262144

    prep_weights<<<dim3(72), dim3(256), 0, stream>>>(Wf, Wi, Wc, Wo, Wch, WgF, WchF);
    lstm_fused<<<dim3(nrows / 1024), dim3(512), 0, stream>>>(
        x, h, c, bf_, bi_, bc_, bo_, bch, WgF, WchF, out, nrows);
}